// Round 13
// baseline (723.984 us; speedup 1.0000x reference)
//
#include <hip/hip_runtime.h>
#include <hip/hip_bf16.h>
#include <math.h>

#define HDIM 512

typedef __attribute__((ext_vector_type(8))) __bf16 bf16x8;
typedef __attribute__((ext_vector_type(2))) __bf16 bf16x2;
typedef __attribute__((ext_vector_type(4))) float f32x4;

#define GLOAD16(src, dst) __builtin_amdgcn_global_load_lds( \
    (const __attribute__((address_space(1))) void*)(src),   \
    (__attribute__((address_space(3))) void*)(dst), 16, 0, 0)

__device__ __forceinline__ float sigmoidf_(float x) { return 1.0f / (1.0f + __expf(-x)); }

// XCD-aware decode: 4 n-blocks of one m-panel -> same XCD (ids congruent mod 8),
// dispatched within 32 linear ids of each other. Bijective incl. remainder tail.
__device__ __forceinline__ void xcd_decode(int L, int nblk4, int& mb, int& nb) {
    int main_part = nblk4 & ~31;
    if (L < main_part) {
        int g = L >> 5, i = L & 31;
        mb = g * 8 + (i & 7);
        nb = i >> 3;
    } else {
        int r = L - main_part;
        mb = (main_part >> 2) + (r >> 2);
        nb = r & 3;
    }
}

// ---------------- all weights fp32 -> bf16, one launch ----------------
__global__ __launch_bounds__(256) void f2bf_all(
    const float* __restrict__ w_z, const float* __restrict__ u_z,
    const float* __restrict__ w_r, const float* __restrict__ u_r,
    const float* __restrict__ w_, const float* __restrict__ u_u,
    const float* __restrict__ w1, const float* __restrict__ w2,
    __bf16* __restrict__ Wzb, __bf16* __restrict__ Uzb,
    __bf16* __restrict__ Wrb, __bf16* __restrict__ Urb,
    __bf16* __restrict__ Wb, __bf16* __restrict__ Ub,
    __bf16* __restrict__ W1b, __bf16* __restrict__ W2b) {
    int bid = blockIdx.x;
    const float* s; __bf16* d; int base;
    if (bid < 1024)      { s = w_z; d = Wzb; base = bid; }
    else if (bid < 2048) { s = u_z; d = Uzb; base = bid - 1024; }
    else if (bid < 3072) { s = w_r; d = Wrb; base = bid - 2048; }
    else if (bid < 4096) { s = u_r; d = Urb; base = bid - 3072; }
    else if (bid < 5120) { s = w_;  d = Wb;  base = bid - 4096; }
    else if (bid < 6144) { s = u_u; d = Ub;  base = bid - 5120; }
    else if (bid < 6656) { s = w1;  d = W1b; base = bid - 6144; }
    else                 { s = w2;  d = W2b; base = bid - 6656; }
    int i = base * 256 + threadIdx.x;
    d[i] = (__bf16)s[i];
}

// ---------------- fused gather + a (iter 0) ----------------
__global__ __launch_bounds__(256) void gather_a(
    const int* __restrict__ ids, const float* __restrict__ emb,
    const float* __restrict__ Ain, const float* __restrict__ bah,
    __bf16* __restrict__ Hbf, __bf16* __restrict__ Abf) {
    int b = blockIdx.x;
    int c2 = threadIdx.x;
    __shared__ float As[169];
    __shared__ int sid[52];
    if (c2 < 169) As[c2] = Ain[b * 169 + c2];
    if (c2 < 52) sid[c2] = ids[b * 52 + c2];
    __syncthreads();
    int c0 = c2 * 2;
    int iseg = c0 >> 7, e = c0 & 127;
    float h0[13], h1[13];
#pragma unroll
    for (int j = 0; j < 13; ++j) {
        int id = sid[iseg * 13 + j];
        float2 hv = *(const float2*)&emb[(size_t)id * 128 + e];
        h0[j] = hv.x;
        h1[j] = hv.y;
        bf16x2 o;
        o[0] = (__bf16)hv.x;
        o[1] = (__bf16)hv.y;
        *(bf16x2*)&Hbf[(size_t)(b * 13 + j) * HDIM + c0] = o;
    }
    float bb0 = bah[c0], bb1 = bah[c0 + 1];
#pragma unroll
    for (int i = 0; i < 13; ++i) {
        float a0 = bb0, a1 = bb1;
#pragma unroll
        for (int j = 0; j < 13; ++j) {
            float a = As[j * 13 + i];
            a0 = fmaf(a, h0[j], a0);
            a1 = fmaf(a, h1[j], a1);
        }
        bf16x2 o;
        o[0] = (__bf16)a0;
        o[1] = (__bf16)a1;
        *(bf16x2*)&Abf[(size_t)(b * 13 + i) * HDIM + c0] = o;
    }
}

// ---------------- a = At @ h + b_ah (iter 1) ----------------
__global__ __launch_bounds__(256) void a_kernel(const float* __restrict__ Ain,
                                                const __bf16* __restrict__ Hbf,
                                                const float* __restrict__ bah,
                                                __bf16* __restrict__ Abf) {
    int b = blockIdx.x;
    int c2 = threadIdx.x;
    __shared__ float As[169];
    if (c2 < 169) As[c2] = Ain[b * 169 + c2];
    float h0[13], h1[13];
#pragma unroll
    for (int j = 0; j < 13; ++j) {
        bf16x2 hv = *(const bf16x2*)&Hbf[(size_t)(b * 13 + j) * HDIM + c2 * 2];
        h0[j] = (float)hv[0];
        h1[j] = (float)hv[1];
    }
    __syncthreads();
    float bb0 = bah[c2 * 2], bb1 = bah[c2 * 2 + 1];
#pragma unroll
    for (int i = 0; i < 13; ++i) {
        float acc0 = bb0, acc1 = bb1;
#pragma unroll
        for (int j = 0; j < 13; ++j) {
            float a = As[j * 13 + i];
            acc0 = fmaf(a, h0[j], acc0);
            acc1 = fmaf(a, h1[j], acc1);
        }
        bf16x2 o;
        o[0] = (__bf16)acc0;
        o[1] = (__bf16)acc1;
        *(bf16x2*)&Abf[(size_t)(b * 13 + i) * HDIM + c2 * 2] = o;
    }
}

// ================= fused z+r GEMM (R9 staging protocol; phase-split MFMA) =================
__global__ __launch_bounds__(512) void zr_fused(
    const __bf16* __restrict__ Abf, const __bf16* __restrict__ Hbf,
    const __bf16* __restrict__ Wz, const __bf16* __restrict__ Uz,
    const __bf16* __restrict__ Wr, const __bf16* __restrict__ Ur,
    const float* __restrict__ bwz, const float* __restrict__ buz,
    const float* __restrict__ bwr, const float* __restrict__ bur,
    __bf16* __restrict__ Zbf, __bf16* __restrict__ RHbf) {
    __shared__ __bf16 lA[2][4096];
    __shared__ __bf16 lB[2][8192];
    int t = threadIdx.x;
    int w = t >> 6, lane = t & 63;
    int role = w & 1;
    int wq = w >> 1;
    int wr2 = wq >> 1, wc2 = wq & 1;
    int mb, nb;
    xcd_decode(blockIdx.x, gridDim.x, mb, nb);
    int m_base = mb * 128;
    int n_base = nb * 128;

    f32x4 acc[4][4];
#pragma unroll
    for (int i = 0; i < 4; ++i)
#pragma unroll
        for (int j = 0; j < 4; ++j)
#pragma unroll
            for (int q = 0; q < 4; ++q) acc[i][j][q] = 0.0f;

    int srow = t >> 2;
    int scol = ((t & 3) ^ ((t >> 3) & 3)) << 3;
    size_t aoff = (size_t)(m_base + srow) * HDIM + scol;
    size_t boff = (size_t)(n_base + srow) * HDIM + scol;
    int frow = lane & 15, kg = lane >> 4;
    int rsl = kg ^ ((frow >> 1) & 3);

    auto stage = [&](int step, int buf) {
        int seg = step >> 4;
        int kc = (step & 15) << 5;
        const __bf16* Xp = seg ? Hbf : Abf;
        const __bf16* B0 = seg ? Uz : Wz;
        const __bf16* B1 = seg ? Ur : Wr;
        GLOAD16(Xp + aoff + kc, &lA[buf][w * 512]);
        GLOAD16(B0 + boff + kc, &lB[buf][w * 512]);
        GLOAD16(B1 + boff + kc, &lB[buf][4096 + w * 512]);
    };

    stage(0, 0);
    int cur = 0;
    for (int step = 0; step < 32; ++step) {
        if (step < 31) {
            stage(step + 1, cur ^ 1);
            asm volatile("s_waitcnt vmcnt(3)" ::: "memory");
        } else {
            asm volatile("s_waitcnt vmcnt(0)" ::: "memory");
        }
        __builtin_amdgcn_s_barrier();
        bf16x8 af[4];
#pragma unroll
        for (int i = 0; i < 4; ++i)
            af[i] = *(const bf16x8*)&lA[cur][(wr2 * 64 + i * 16 + frow) * 32 + rsl * 8];
        // phase-split: per j-quadrant {bfr read, MFMA cluster, barrier}
#pragma unroll
        for (int j = 0; j < 4; ++j) {
            bf16x8 bfr = *(const bf16x8*)&lB[cur][role * 4096 + (wc2 * 64 + j * 16 + frow) * 32 + rsl * 8];
            __builtin_amdgcn_s_setprio(1);
#pragma unroll
            for (int i = 0; i < 4; ++i)
                acc[i][j] = __builtin_amdgcn_mfma_f32_16x16x32_bf16(af[i], bfr, acc[i][j], 0, 0, 0);
            __builtin_amdgcn_s_setprio(0);
            __builtin_amdgcn_s_barrier();
        }
        cur ^= 1;
    }

    int frow4 = (lane >> 4) * 4;
    int fcol = lane & 15;
#pragma unroll
    for (int i = 0; i < 4; ++i) {
#pragma unroll
        for (int j = 0; j < 4; ++j) {
            int col = n_base + wc2 * 64 + j * 16 + fcol;
            float bias = role ? (bwr[col] + bur[col]) : (bwz[col] + buz[col]);
            int rbase = m_base + wr2 * 64 + i * 16 + frow4;
#pragma unroll
            for (int q = 0; q < 4; ++q) {
                size_t off = (size_t)(rbase + q) * HDIM + col;
                float v = sigmoidf_(acc[i][j][q] + bias);
                if (role) {
                    RHbf[off] = (__bf16)(v * (float)Hbf[off]);
                } else {
                    Zbf[off] = (__bf16)v;
                }
            }
        }
    }
}

// ================= c GEMM + gated update (R9 staging protocol; phase-split MFMA) =================
__global__ __launch_bounds__(512) void c_fused(
    const __bf16* __restrict__ Abf, const __bf16* __restrict__ RHbf,
    const __bf16* __restrict__ W, const __bf16* __restrict__ U,
    const float* __restrict__ bw, const float* __restrict__ bu,
    const __bf16* __restrict__ Zbf, __bf16* __restrict__ Hbf) {
    __shared__ __bf16 lA[2][4096];
    __shared__ __bf16 lB[2][4096];
    int t = threadIdx.x;
    int w = t >> 6, lane = t & 63;
    int wr = w >> 2, wc = w & 3;
    int mb, nb;
    xcd_decode(blockIdx.x, gridDim.x, mb, nb);
    int m_base = mb * 128;
    int n_base = nb * 128;

    f32x4 acc[4][2];
#pragma unroll
    for (int i = 0; i < 4; ++i)
#pragma unroll
        for (int j = 0; j < 2; ++j)
#pragma unroll
            for (int q = 0; q < 4; ++q) acc[i][j][q] = 0.0f;

    int srow = t >> 2;
    int scol = ((t & 3) ^ ((t >> 3) & 3)) << 3;
    size_t aoff = (size_t)(m_base + srow) * HDIM + scol;
    size_t boff = (size_t)(n_base + srow) * HDIM + scol;
    int frow = lane & 15, kg = lane >> 4;
    int rsl = kg ^ ((frow >> 1) & 3);

    auto stage = [&](int step, int buf) {
        int seg = step >> 4;
        int kc = (step & 15) << 5;
        const __bf16* Xp = seg ? RHbf : Abf;
        const __bf16* Wp = seg ? U : W;
        GLOAD16(Xp + aoff + kc, &lA[buf][w * 512]);
        GLOAD16(Wp + boff + kc, &lB[buf][w * 512]);
    };

    stage(0, 0);
    int cur = 0;
    for (int step = 0; step < 32; ++step) {
        if (step < 31) {
            stage(step + 1, cur ^ 1);
            asm volatile("s_waitcnt vmcnt(2)" ::: "memory");
        } else {
            asm volatile("s_waitcnt vmcnt(0)" ::: "memory");
        }
        __builtin_amdgcn_s_barrier();
        bf16x8 af[4];
#pragma unroll
        for (int i = 0; i < 4; ++i)
            af[i] = *(const bf16x8*)&lA[cur][(wr * 64 + i * 16 + frow) * 32 + rsl * 8];
#pragma unroll
        for (int j = 0; j < 2; ++j) {
            bf16x8 bfr = *(const bf16x8*)&lB[cur][(wc * 32 + j * 16 + frow) * 32 + rsl * 8];
            __builtin_amdgcn_s_setprio(1);
#pragma unroll
            for (int i = 0; i < 4; ++i)
                acc[i][j] = __builtin_amdgcn_mfma_f32_16x16x32_bf16(af[i], bfr, acc[i][j], 0, 0, 0);
            __builtin_amdgcn_s_setprio(0);
            __builtin_amdgcn_s_barrier();
        }
        cur ^= 1;
    }

    int frow4 = (lane >> 4) * 4;
    int fcol = lane & 15;
#pragma unroll
    for (int i = 0; i < 4; ++i) {
#pragma unroll
        for (int j = 0; j < 2; ++j) {
            int col = n_base + wc * 32 + j * 16 + fcol;
            float bias = bw[col] + bu[col];
            int rbase = m_base + wr * 64 + i * 16 + frow4;
#pragma unroll
            for (int q = 0; q < 4; ++q) {
                size_t off = (size_t)(rbase + q) * HDIM + col;
                float v = acc[i][j][q] + bias;
                float x = v > 15.0f ? 15.0f : (v < -15.0f ? -15.0f : v);
                float e = __expf(2.0f * x);
                float cv = (e - 1.0f) / (e + 1.0f);
                float h = (float)Hbf[off];
                float z = (float)Zbf[off];
                float hn = (1.0f - z) * h + z * cv;
                Hbf[off] = (__bf16)hn;
            }
        }
    }
}

// ================= merged scorer: bf16 MFMA GEMM (Mx256, K=512) =================
__global__ __launch_bounds__(512) void score_mfma(
    const __bf16* __restrict__ Hbf,
    const __bf16* __restrict__ W1b, const __bf16* __restrict__ W2b,
    const float* __restrict__ b1A, const float* __restrict__ b1B,
    const float* __restrict__ wsA, const float* __restrict__ wsB,
    const float* __restrict__ b2A, const float* __restrict__ b2B,
    float* __restrict__ UA, float* __restrict__ UB, int nblkA) {
    __shared__ __bf16 lA[2][4096];
    __shared__ __bf16 lB[2][8192];
    __shared__ float red[128][5];
    int t = threadIdx.x;
    int w = t >> 6, lane = t & 63;
    int wr = w >> 2, wc = w & 3;

    const __bf16* Wb;
    const float* bias1;
    const float* wsm;
    const float* bias2;
    float* outv;
    int inner, off, m_base;
    if ((int)blockIdx.x < nblkA) {
        Wb = W1b; bias1 = b1A; wsm = wsA; bias2 = b2A; outv = UA;
        inner = 8; off = 0; m_base = blockIdx.x * 128;
    } else {
        Wb = W2b; bias1 = b1B; wsm = wsB; bias2 = b2B; outv = UB;
        inner = 5; off = 8; m_base = (blockIdx.x - nblkA) * 128;
    }

    f32x4 acc[4][4];
#pragma unroll
    for (int i = 0; i < 4; ++i)
#pragma unroll
        for (int j = 0; j < 4; ++j)
#pragma unroll
            for (int q = 0; q < 4; ++q) acc[i][j][q] = 0.0f;

    int srow = t >> 2;
    int scol = ((t & 3) ^ ((t >> 3) & 3)) << 3;
    int mrow = m_base + srow;
    int hrow = (mrow / inner) * 13 + off + (mrow % inner);
    size_t aoff = (size_t)hrow * HDIM + scol;
    size_t boff = (size_t)srow * HDIM + scol;
    int frow = lane & 15, kg = lane >> 4;
    int rsl = kg ^ ((frow >> 1) & 3);

    auto stage = [&](int step, int buf) {
        int kc = step << 5;
        GLOAD16(Hbf + aoff + kc, &lA[buf][w * 512]);
        GLOAD16(Wb + boff + kc, &lB[buf][w * 512]);
        GLOAD16(Wb + boff + (size_t)128 * HDIM + kc, &lB[buf][4096 + w * 512]);
    };

    stage(0, 0);
    int cur = 0;
    for (int step = 0; step < 16; ++step) {
        if (step < 15) {
            stage(step + 1, cur ^ 1);
            asm volatile("s_waitcnt vmcnt(3)" ::: "memory");
        } else {
            asm volatile("s_waitcnt vmcnt(0)" ::: "memory");
        }
        __builtin_amdgcn_s_barrier();
        bf16x8 af[4], bfr[4];
#pragma unroll
        for (int i = 0; i < 4; ++i) {
            af[i] = *(const bf16x8*)&lA[cur][(wr * 64 + i * 16 + frow) * 32 + rsl * 8];
            bfr[i] = *(const bf16x8*)&lB[cur][(wc * 64 + i * 16 + frow) * 32 + rsl * 8];
        }
        __builtin_amdgcn_s_setprio(1);
#pragma unroll
        for (int i = 0; i < 4; ++i)
#pragma unroll
            for (int j = 0; j < 4; ++j)
                acc[i][j] = __builtin_amdgcn_mfma_f32_16x16x32_bf16(af[i], bfr[j], acc[i][j], 0, 0, 0);
        __builtin_amdgcn_s_setprio(0);
        __builtin_amdgcn_s_barrier();
        cur ^= 1;
    }

    int frow4 = (lane >> 4) * 4;
    int fcol = lane & 15;
#pragma unroll
    for (int i = 0; i < 4; ++i) {
#pragma unroll
        for (int q = 0; q < 4; ++q) {
            float s = 0.0f;
#pragma unroll
            for (int j = 0; j < 4; ++j) {
                int col = wc * 64 + j * 16 + fcol;
                float v = acc[i][j][q] + bias1[col];
                v = v > 0.0f ? v : 0.0f;
                s = fmaf(v, wsm[col], s);
            }
            s += __shfl_xor(s, 1);
            s += __shfl_xor(s, 2);
            s += __shfl_xor(s, 4);
            s += __shfl_xor(s, 8);
            if (fcol == 0) red[wr * 64 + i * 16 + frow4 + q][wc] = s;
        }
    }
    __syncthreads();
    if (t < 128) {
        float s = red[t][0] + red[t][1] + red[t][2] + red[t][3] + bias2[0];
        outv[m_base + t] = s > 0.0f ? s : 0.0f;
    }
}

// ---------------- final: softmax over 8 ctx nodes, weighted sum, -L2 distance (bf16 h) ----------------
__global__ __launch_bounds__(256) void final_kernel(const __bf16* __restrict__ Hbf,
                                                    const float* __restrict__ UAv,
                                                    const float* __restrict__ UBv,
                                                    float* __restrict__ outv) {
    int b = blockIdx.x;
    int t = threadIdx.x;
    __shared__ float ctx[8][512];
    __shared__ float uas[8], ubs[5];
    __shared__ float red[4];
#pragma unroll
    for (int q = 0; q < 8; ++q) {
        int idx = q * 256 + t;
        int j = idx >> 8, c = (idx & 255) * 2;
        bf16x2 hv = *(const bf16x2*)&Hbf[(size_t)(b * 13 + j) * HDIM + c];
        ctx[j][c] = (float)hv[0];
        ctx[j][c + 1] = (float)hv[1];
    }
    if (t < 8) uas[t] = UAv[b * 8 + t];
    if (t < 5) ubs[t] = UBv[b * 5 + t];
    __syncthreads();
    int c0 = t, c1 = t + 256;
    int wid = t >> 6, lane = t & 63;
    for (int s = 0; s < 5; ++s) {
        float wn[8];
        float sum = 0.0f;
#pragma unroll
        for (int j = 0; j < 8; ++j) {
            wn[j] = __expf(tanhf(uas[j] + ubs[s]));
            sum += wn[j];
        }
        float inv = 1.0f / sum;
        float av0 = 0.0f, av1 = 0.0f;
#pragma unroll
        for (int j = 0; j < 8; ++j) {
            av0 = fmaf(wn[j], ctx[j][c0], av0);
            av1 = fmaf(wn[j], ctx[j][c1], av1);
        }
        av0 *= inv;
        av1 *= inv;
        float d0 = av0 - (float)Hbf[(size_t)(b * 13 + 8 + s) * HDIM + c0];
        float d1 = av1 - (float)Hbf[(size_t)(b * 13 + 8 + s) * HDIM + c1];
        float v = d0 * d0 + d1 * d1;
#pragma unroll
        for (int o = 32; o > 0; o >>= 1) v += __shfl_down(v, o);
        if (lane == 0) red[wid] = v;
        __syncthreads();
        if (t == 0) outv[b * 5 + s] = -sqrtf(red[0] + red[1] + red[2] + red[3]);
        __syncthreads();
    }
}

extern "C" void kernel_launch(void* const* d_in, const int* in_sizes, int n_in,
                              void* d_out, int out_size, void* d_ws, size_t ws_size,
                              hipStream_t stream) {
    const float* Ain  = (const float*)d_in[0];
    const int*   ids  = (const int*)d_in[1];
    const float* emb  = (const float*)d_in[2];
    const float* b_ah = (const float*)d_in[3];
    const float* w_z  = (const float*)d_in[4];
    const float* b_wz = (const float*)d_in[5];
    const float* u_z  = (const float*)d_in[6];
    const float* b_uz = (const float*)d_in[7];
    const float* w_r  = (const float*)d_in[8];
    const float* b_wr = (const float*)d_in[9];
    const float* u_r  = (const float*)d_in[10];
    const float* b_ur = (const float*)d_in[11];
    const float* w_   = (const float*)d_in[12];
    const float* b_w  = (const float*)d_in[13];
    const float* u_u  = (const float*)d_in[14];
    const float* b_u  = (const float*)d_in[15];
    const float* w1   = (const float*)d_in[16];
    const float* b1   = (const float*)d_in[17];
    const float* w12  = (const float*)d_in[18];
    const float* b12  = (const float*)d_in[19];
    const float* w2   = (const float*)d_in[20];
    const float* b2   = (const float*)d_in[21];
    const float* w22  = (const float*)d_in[22];
    const float* b22  = (const float*)d_in[23];
    float* out = (float*)d_out;

    // ---- chunk size: rows=13C divisible by 128 -> C multiple of 128 ----
    // per-elem: Hbf2 + Abf2 + RHbf2 + Zbf2 = 8B
    int C = 128;
    {
        const int cands[6] = {4096, 2048, 1024, 512, 256, 128};
        for (int ci = 0; ci < 6; ++ci) {
            int cc = cands[ci];
            size_t rows = (size_t)13 * cc;
            size_t need = rows * 512 * 8
                        + 6 * (size_t)262144 * 2
                        + 2 * (size_t)131072 * 2
                        + (size_t)13 * cc * 4
                        + (4u << 20);
            if (need <= ws_size) { C = cc; break; }
        }
    }
    const int rows = 13 * C;

    char* base = (char*)d_ws;
    __bf16* Wzb = (__bf16*)base; base += 262144 * 2;
    __bf16* Uzb = (__bf16*)base; base += 262144 * 2;
    __bf16* Wrb = (__bf16*)base; base += 262144 * 2;
    __bf16* Urb = (__bf16*)base; base += 262144 * 2;
    __bf16* Wb  = (__bf16*)base; base += 262144 * 2;
    __bf16* Ub  = (__bf16*)base; base += 262144 * 2;
    __bf16* W1b = (__bf16*)base; base += 131072 * 2;
    __bf16* W2b = (__bf16*)base; base += 131072 * 2;
    float* UA  = (float*)base; base += (size_t)8 * C * 4;
    float* UB  = (float*)base; base += (size_t)5 * C * 4;
    __bf16* Hbf  = (__bf16*)base; base += (size_t)rows * 512 * 2;
    __bf16* Abf  = (__bf16*)base; base += (size_t)rows * 512 * 2;
    __bf16* RHbf = (__bf16*)base; base += (size_t)rows * 512 * 2;
    __bf16* Zbf  = (__bf16*)base; base += (size_t)rows * 512 * 2;

    f2bf_all<<<7168, 256, 0, stream>>>(w_z, u_z, w_r, u_r, w_, u_u, w1, w2,
                                       Wzb, Uzb, Wrb, Urb, Wb, Ub, W1b, W2b);

    int nblk4 = (rows / 128) * 4;
    int nblkA = 8 * C / 128;
    int nblkB = 5 * C / 128;
    for (int g0 = 0; g0 < 4096; g0 += C) {
        gather_a<<<C, 256, 0, stream>>>(ids + (size_t)g0 * 52, emb,
                                        Ain + (size_t)g0 * 169, b_ah, Hbf, Abf);
        zr_fused<<<nblk4, 512, 0, stream>>>(Abf, Hbf, Wzb, Uzb, Wrb, Urb,
                                            b_wz, b_uz, b_wr, b_ur, Zbf, RHbf);
        c_fused<<<nblk4, 512, 0, stream>>>(Abf, RHbf, Wb, Ub, b_w, b_u, Zbf, Hbf);
        a_kernel<<<C, 256, 0, stream>>>(Ain + (size_t)g0 * 169, Hbf, b_ah, Abf);
        zr_fused<<<nblk4, 512, 0, stream>>>(Abf, Hbf, Wzb, Uzb, Wrb, Urb,
                                            b_wz, b_uz, b_wr, b_ur, Zbf, RHbf);
        c_fused<<<nblk4, 512, 0, stream>>>(Abf, RHbf, Wb, Ub, b_w, b_u, Zbf, Hbf);

        score_mfma<<<nblkA + nblkB, 512, 0, stream>>>(Hbf, W1b, W2b, b1, b2, w12, w22,
                                                      b12, b22, UA, UB, nblkA);
        final_kernel<<<C, 256, 0, stream>>>(Hbf, UA, UB, out + (size_t)g0 * 5);
    }
}

// Round 14
// 688.739 us; speedup vs baseline: 1.0512x; 1.0512x over previous
//
#include <hip/hip_runtime.h>
#include <hip/hip_bf16.h>
#include <math.h>

#define HDIM 512

typedef __attribute__((ext_vector_type(8))) __bf16 bf16x8;
typedef __attribute__((ext_vector_type(2))) __bf16 bf16x2;
typedef __attribute__((ext_vector_type(4))) float f32x4;

#define GLOAD16(src, dst) __builtin_amdgcn_global_load_lds( \
    (const __attribute__((address_space(1))) void*)(src),   \
    (__attribute__((address_space(3))) void*)(dst), 16, 0, 0)

__device__ __forceinline__ float sigmoidf_(float x) { return 1.0f / (1.0f + __expf(-x)); }

// XCD-aware decode: 4 n-blocks of one m-panel -> same XCD (ids congruent mod 8),
// dispatched within 32 linear ids of each other. Bijective incl. remainder tail.
__device__ __forceinline__ void xcd_decode(int L, int nblk4, int& mb, int& nb) {
    int main_part = nblk4 & ~31;
    if (L < main_part) {
        int g = L >> 5, i = L & 31;
        mb = g * 8 + (i & 7);
        nb = i >> 3;
    } else {
        int r = L - main_part;
        mb = (main_part >> 2) + (r >> 2);
        nb = r & 3;
    }
}

// ---------------- all weights fp32 -> bf16, one launch ----------------
__global__ __launch_bounds__(256) void f2bf_all(
    const float* __restrict__ w_z, const float* __restrict__ u_z,
    const float* __restrict__ w_r, const float* __restrict__ u_r,
    const float* __restrict__ w_, const float* __restrict__ u_u,
    const float* __restrict__ w1, const float* __restrict__ w2,
    __bf16* __restrict__ Wzb, __bf16* __restrict__ Uzb,
    __bf16* __restrict__ Wrb, __bf16* __restrict__ Urb,
    __bf16* __restrict__ Wb, __bf16* __restrict__ Ub,
    __bf16* __restrict__ W1b, __bf16* __restrict__ W2b) {
    int bid = blockIdx.x;
    const float* s; __bf16* d; int base;
    if (bid < 1024)      { s = w_z; d = Wzb; base = bid; }
    else if (bid < 2048) { s = u_z; d = Uzb; base = bid - 1024; }
    else if (bid < 3072) { s = w_r; d = Wrb; base = bid - 2048; }
    else if (bid < 4096) { s = u_r; d = Urb; base = bid - 3072; }
    else if (bid < 5120) { s = w_;  d = Wb;  base = bid - 4096; }
    else if (bid < 6144) { s = u_u; d = Ub;  base = bid - 5120; }
    else if (bid < 6656) { s = w1;  d = W1b; base = bid - 6144; }
    else                 { s = w2;  d = W2b; base = bid - 6656; }
    int i = base * 256 + threadIdx.x;
    d[i] = (__bf16)s[i];
}

// ---------------- fused gather + a (iter 0) ----------------
__global__ __launch_bounds__(256) void gather_a(
    const int* __restrict__ ids, const float* __restrict__ emb,
    const float* __restrict__ Ain, const float* __restrict__ bah,
    __bf16* __restrict__ Hbf, __bf16* __restrict__ Abf) {
    int b = blockIdx.x;
    int c2 = threadIdx.x;
    __shared__ float As[169];
    __shared__ int sid[52];
    if (c2 < 169) As[c2] = Ain[b * 169 + c2];
    if (c2 < 52) sid[c2] = ids[b * 52 + c2];
    __syncthreads();
    int c0 = c2 * 2;
    int iseg = c0 >> 7, e = c0 & 127;
    float h0[13], h1[13];
#pragma unroll
    for (int j = 0; j < 13; ++j) {
        int id = sid[iseg * 13 + j];
        float2 hv = *(const float2*)&emb[(size_t)id * 128 + e];
        h0[j] = hv.x;
        h1[j] = hv.y;
        bf16x2 o;
        o[0] = (__bf16)hv.x;
        o[1] = (__bf16)hv.y;
        *(bf16x2*)&Hbf[(size_t)(b * 13 + j) * HDIM + c0] = o;
    }
    float bb0 = bah[c0], bb1 = bah[c0 + 1];
#pragma unroll
    for (int i = 0; i < 13; ++i) {
        float a0 = bb0, a1 = bb1;
#pragma unroll
        for (int j = 0; j < 13; ++j) {
            float a = As[j * 13 + i];
            a0 = fmaf(a, h0[j], a0);
            a1 = fmaf(a, h1[j], a1);
        }
        bf16x2 o;
        o[0] = (__bf16)a0;
        o[1] = (__bf16)a1;
        *(bf16x2*)&Abf[(size_t)(b * 13 + i) * HDIM + c0] = o;
    }
}

// ---------------- a = At @ h + b_ah (iter 1) ----------------
__global__ __launch_bounds__(256) void a_kernel(const float* __restrict__ Ain,
                                                const __bf16* __restrict__ Hbf,
                                                const float* __restrict__ bah,
                                                __bf16* __restrict__ Abf) {
    int b = blockIdx.x;
    int c2 = threadIdx.x;
    __shared__ float As[169];
    if (c2 < 169) As[c2] = Ain[b * 169 + c2];
    float h0[13], h1[13];
#pragma unroll
    for (int j = 0; j < 13; ++j) {
        bf16x2 hv = *(const bf16x2*)&Hbf[(size_t)(b * 13 + j) * HDIM + c2 * 2];
        h0[j] = (float)hv[0];
        h1[j] = (float)hv[1];
    }
    __syncthreads();
    float bb0 = bah[c2 * 2], bb1 = bah[c2 * 2 + 1];
#pragma unroll
    for (int i = 0; i < 13; ++i) {
        float acc0 = bb0, acc1 = bb1;
#pragma unroll
        for (int j = 0; j < 13; ++j) {
            float a = As[j * 13 + i];
            acc0 = fmaf(a, h0[j], acc0);
            acc1 = fmaf(a, h1[j], acc1);
        }
        bf16x2 o;
        o[0] = (__bf16)acc0;
        o[1] = (__bf16)acc1;
        *(bf16x2*)&Abf[(size_t)(b * 13 + i) * HDIM + c2 * 2] = o;
    }
}

// ================= fused z+r GEMM (R9 proven loop; XCD-swizzled 1D grid) =================
__global__ __launch_bounds__(512) void zr_fused(
    const __bf16* __restrict__ Abf, const __bf16* __restrict__ Hbf,
    const __bf16* __restrict__ Wz, const __bf16* __restrict__ Uz,
    const __bf16* __restrict__ Wr, const __bf16* __restrict__ Ur,
    const float* __restrict__ bwz, const float* __restrict__ buz,
    const float* __restrict__ bwr, const float* __restrict__ bur,
    __bf16* __restrict__ Zbf, __bf16* __restrict__ RHbf) {
    __shared__ __bf16 lA[2][4096];
    __shared__ __bf16 lB[2][8192];
    int t = threadIdx.x;
    int w = t >> 6, lane = t & 63;
    int role = w & 1;
    int wq = w >> 1;
    int wr2 = wq >> 1, wc2 = wq & 1;
    int mb, nb;
    xcd_decode(blockIdx.x, gridDim.x, mb, nb);
    int m_base = mb * 128;
    int n_base = nb * 128;

    f32x4 acc[4][4];
#pragma unroll
    for (int i = 0; i < 4; ++i)
#pragma unroll
        for (int j = 0; j < 4; ++j)
#pragma unroll
            for (int q = 0; q < 4; ++q) acc[i][j][q] = 0.0f;

    int srow = t >> 2;
    int scol = ((t & 3) ^ ((t >> 3) & 3)) << 3;
    size_t aoff = (size_t)(m_base + srow) * HDIM + scol;
    size_t boff = (size_t)(n_base + srow) * HDIM + scol;
    int frow = lane & 15, kg = lane >> 4;
    int rsl = kg ^ ((frow >> 1) & 3);

    auto stage = [&](int step, int buf) {
        int seg = step >> 4;
        int kc = (step & 15) << 5;
        const __bf16* Xp = seg ? Hbf : Abf;
        const __bf16* B0 = seg ? Uz : Wz;
        const __bf16* B1 = seg ? Ur : Wr;
        GLOAD16(Xp + aoff + kc, &lA[buf][w * 512]);
        GLOAD16(B0 + boff + kc, &lB[buf][w * 512]);
        GLOAD16(B1 + boff + kc, &lB[buf][4096 + w * 512]);
    };

    stage(0, 0);
    int cur = 0;
    for (int step = 0; step < 32; ++step) {
        if (step < 31) {
            stage(step + 1, cur ^ 1);
            asm volatile("s_waitcnt vmcnt(3)" ::: "memory");
        } else {
            asm volatile("s_waitcnt vmcnt(0)" ::: "memory");
        }
        __builtin_amdgcn_s_barrier();
        bf16x8 af[4], bfr[4];
#pragma unroll
        for (int i = 0; i < 4; ++i) {
            af[i] = *(const bf16x8*)&lA[cur][(wr2 * 64 + i * 16 + frow) * 32 + rsl * 8];
            bfr[i] = *(const bf16x8*)&lB[cur][role * 4096 + (wc2 * 64 + i * 16 + frow) * 32 + rsl * 8];
        }
        __builtin_amdgcn_s_setprio(1);
#pragma unroll
        for (int i = 0; i < 4; ++i)
#pragma unroll
            for (int j = 0; j < 4; ++j)
                acc[i][j] = __builtin_amdgcn_mfma_f32_16x16x32_bf16(af[i], bfr[j], acc[i][j], 0, 0, 0);
        __builtin_amdgcn_s_setprio(0);
        __builtin_amdgcn_s_barrier();
        cur ^= 1;
    }

    int frow4 = (lane >> 4) * 4;
    int fcol = lane & 15;
#pragma unroll
    for (int i = 0; i < 4; ++i) {
#pragma unroll
        for (int j = 0; j < 4; ++j) {
            int col = n_base + wc2 * 64 + j * 16 + fcol;
            float bias = role ? (bwr[col] + bur[col]) : (bwz[col] + buz[col]);
            int rbase = m_base + wr2 * 64 + i * 16 + frow4;
#pragma unroll
            for (int q = 0; q < 4; ++q) {
                size_t off = (size_t)(rbase + q) * HDIM + col;
                float v = sigmoidf_(acc[i][j][q] + bias);
                if (role) {
                    RHbf[off] = (__bf16)(v * (float)Hbf[off]);
                } else {
                    Zbf[off] = (__bf16)v;
                }
            }
        }
    }
}

// ================= c GEMM + gated update (R9 proven loop; XCD-swizzled 1D grid) =================
__global__ __launch_bounds__(512) void c_fused(
    const __bf16* __restrict__ Abf, const __bf16* __restrict__ RHbf,
    const __bf16* __restrict__ W, const __bf16* __restrict__ U,
    const float* __restrict__ bw, const float* __restrict__ bu,
    const __bf16* __restrict__ Zbf, __bf16* __restrict__ Hbf) {
    __shared__ __bf16 lA[2][4096];
    __shared__ __bf16 lB[2][4096];
    int t = threadIdx.x;
    int w = t >> 6, lane = t & 63;
    int wr = w >> 2, wc = w & 3;
    int mb, nb;
    xcd_decode(blockIdx.x, gridDim.x, mb, nb);
    int m_base = mb * 128;
    int n_base = nb * 128;

    f32x4 acc[4][2];
#pragma unroll
    for (int i = 0; i < 4; ++i)
#pragma unroll
        for (int j = 0; j < 2; ++j)
#pragma unroll
            for (int q = 0; q < 4; ++q) acc[i][j][q] = 0.0f;

    int srow = t >> 2;
    int scol = ((t & 3) ^ ((t >> 3) & 3)) << 3;
    size_t aoff = (size_t)(m_base + srow) * HDIM + scol;
    size_t boff = (size_t)(n_base + srow) * HDIM + scol;
    int frow = lane & 15, kg = lane >> 4;
    int rsl = kg ^ ((frow >> 1) & 3);

    auto stage = [&](int step, int buf) {
        int seg = step >> 4;
        int kc = (step & 15) << 5;
        const __bf16* Xp = seg ? RHbf : Abf;
        const __bf16* Wp = seg ? U : W;
        GLOAD16(Xp + aoff + kc, &lA[buf][w * 512]);
        GLOAD16(Wp + boff + kc, &lB[buf][w * 512]);
    };

    stage(0, 0);
    int cur = 0;
    for (int step = 0; step < 32; ++step) {
        if (step < 31) {
            stage(step + 1, cur ^ 1);
            asm volatile("s_waitcnt vmcnt(2)" ::: "memory");
        } else {
            asm volatile("s_waitcnt vmcnt(0)" ::: "memory");
        }
        __builtin_amdgcn_s_barrier();
        bf16x8 af[4], bfr[2];
#pragma unroll
        for (int i = 0; i < 4; ++i)
            af[i] = *(const bf16x8*)&lA[cur][(wr * 64 + i * 16 + frow) * 32 + rsl * 8];
#pragma unroll
        for (int j = 0; j < 2; ++j)
            bfr[j] = *(const bf16x8*)&lB[cur][(wc * 32 + j * 16 + frow) * 32 + rsl * 8];
        __builtin_amdgcn_s_setprio(1);
#pragma unroll
        for (int i = 0; i < 4; ++i)
#pragma unroll
            for (int j = 0; j < 2; ++j)
                acc[i][j] = __builtin_amdgcn_mfma_f32_16x16x32_bf16(af[i], bfr[j], acc[i][j], 0, 0, 0);
        __builtin_amdgcn_s_setprio(0);
        __builtin_amdgcn_s_barrier();
        cur ^= 1;
    }

    int frow4 = (lane >> 4) * 4;
    int fcol = lane & 15;
#pragma unroll
    for (int i = 0; i < 4; ++i) {
#pragma unroll
        for (int j = 0; j < 2; ++j) {
            int col = n_base + wc * 32 + j * 16 + fcol;
            float bias = bw[col] + bu[col];
            int rbase = m_base + wr * 64 + i * 16 + frow4;
#pragma unroll
            for (int q = 0; q < 4; ++q) {
                size_t off = (size_t)(rbase + q) * HDIM + col;
                float v = acc[i][j][q] + bias;
                float x = v > 15.0f ? 15.0f : (v < -15.0f ? -15.0f : v);
                float e = __expf(2.0f * x);
                float cv = (e - 1.0f) / (e + 1.0f);
                float h = (float)Hbf[off];
                float z = (float)Zbf[off];
                float hn = (1.0f - z) * h + z * cv;
                Hbf[off] = (__bf16)hn;
            }
        }
    }
}

// ================= merged scorer: bf16 MFMA GEMM (Mx256, K=512) =================
__global__ __launch_bounds__(512) void score_mfma(
    const __bf16* __restrict__ Hbf,
    const __bf16* __restrict__ W1b, const __bf16* __restrict__ W2b,
    const float* __restrict__ b1A, const float* __restrict__ b1B,
    const float* __restrict__ wsA, const float* __restrict__ wsB,
    const float* __restrict__ b2A, const float* __restrict__ b2B,
    float* __restrict__ UA, float* __restrict__ UB, int nblkA) {
    __shared__ __bf16 lA[2][4096];
    __shared__ __bf16 lB[2][8192];
    __shared__ float red[128][5];
    int t = threadIdx.x;
    int w = t >> 6, lane = t & 63;
    int wr = w >> 2, wc = w & 3;

    const __bf16* Wb;
    const float* bias1;
    const float* wsm;
    const float* bias2;
    float* outv;
    int inner, off, m_base;
    if ((int)blockIdx.x < nblkA) {
        Wb = W1b; bias1 = b1A; wsm = wsA; bias2 = b2A; outv = UA;
        inner = 8; off = 0; m_base = blockIdx.x * 128;
    } else {
        Wb = W2b; bias1 = b1B; wsm = wsB; bias2 = b2B; outv = UB;
        inner = 5; off = 8; m_base = (blockIdx.x - nblkA) * 128;
    }

    f32x4 acc[4][4];
#pragma unroll
    for (int i = 0; i < 4; ++i)
#pragma unroll
        for (int j = 0; j < 4; ++j)
#pragma unroll
            for (int q = 0; q < 4; ++q) acc[i][j][q] = 0.0f;

    int srow = t >> 2;
    int scol = ((t & 3) ^ ((t >> 3) & 3)) << 3;
    int mrow = m_base + srow;
    int hrow = (mrow / inner) * 13 + off + (mrow % inner);
    size_t aoff = (size_t)hrow * HDIM + scol;
    size_t boff = (size_t)srow * HDIM + scol;
    int frow = lane & 15, kg = lane >> 4;
    int rsl = kg ^ ((frow >> 1) & 3);

    auto stage = [&](int step, int buf) {
        int kc = step << 5;
        GLOAD16(Hbf + aoff + kc, &lA[buf][w * 512]);
        GLOAD16(Wb + boff + kc, &lB[buf][w * 512]);
        GLOAD16(Wb + boff + (size_t)128 * HDIM + kc, &lB[buf][4096 + w * 512]);
    };

    stage(0, 0);
    int cur = 0;
    for (int step = 0; step < 16; ++step) {
        if (step < 15) {
            stage(step + 1, cur ^ 1);
            asm volatile("s_waitcnt vmcnt(3)" ::: "memory");
        } else {
            asm volatile("s_waitcnt vmcnt(0)" ::: "memory");
        }
        __builtin_amdgcn_s_barrier();
        bf16x8 af[4], bfr[4];
#pragma unroll
        for (int i = 0; i < 4; ++i) {
            af[i] = *(const bf16x8*)&lA[cur][(wr * 64 + i * 16 + frow) * 32 + rsl * 8];
            bfr[i] = *(const bf16x8*)&lB[cur][(wc * 64 + i * 16 + frow) * 32 + rsl * 8];
        }
        __builtin_amdgcn_s_setprio(1);
#pragma unroll
        for (int i = 0; i < 4; ++i)
#pragma unroll
            for (int j = 0; j < 4; ++j)
                acc[i][j] = __builtin_amdgcn_mfma_f32_16x16x32_bf16(af[i], bfr[j], acc[i][j], 0, 0, 0);
        __builtin_amdgcn_s_setprio(0);
        __builtin_amdgcn_s_barrier();
        cur ^= 1;
    }

    int frow4 = (lane >> 4) * 4;
    int fcol = lane & 15;
#pragma unroll
    for (int i = 0; i < 4; ++i) {
#pragma unroll
        for (int q = 0; q < 4; ++q) {
            float s = 0.0f;
#pragma unroll
            for (int j = 0; j < 4; ++j) {
                int col = wc * 64 + j * 16 + fcol;
                float v = acc[i][j][q] + bias1[col];
                v = v > 0.0f ? v : 0.0f;
                s = fmaf(v, wsm[col], s);
            }
            s += __shfl_xor(s, 1);
            s += __shfl_xor(s, 2);
            s += __shfl_xor(s, 4);
            s += __shfl_xor(s, 8);
            if (fcol == 0) red[wr * 64 + i * 16 + frow4 + q][wc] = s;
        }
    }
    __syncthreads();
    if (t < 128) {
        float s = red[t][0] + red[t][1] + red[t][2] + red[t][3] + bias2[0];
        outv[m_base + t] = s > 0.0f ? s : 0.0f;
    }
}

// ---------------- final: softmax over 8 ctx nodes, weighted sum, -L2 distance (bf16 h) ----------------
__global__ __launch_bounds__(256) void final_kernel(const __bf16* __restrict__ Hbf,
                                                    const float* __restrict__ UAv,
                                                    const float* __restrict__ UBv,
                                                    float* __restrict__ outv) {
    int b = blockIdx.x;
    int t = threadIdx.x;
    __shared__ float ctx[8][512];
    __shared__ float uas[8], ubs[5];
    __shared__ float red[4];
#pragma unroll
    for (int q = 0; q < 8; ++q) {
        int idx = q * 256 + t;
        int j = idx >> 8, c = (idx & 255) * 2;
        bf16x2 hv = *(const bf16x2*)&Hbf[(size_t)(b * 13 + j) * HDIM + c];
        ctx[j][c] = (float)hv[0];
        ctx[j][c + 1] = (float)hv[1];
    }
    if (t < 8) uas[t] = UAv[b * 8 + t];
    if (t < 5) ubs[t] = UBv[b * 5 + t];
    __syncthreads();
    int c0 = t, c1 = t + 256;
    int wid = t >> 6, lane = t & 63;
    for (int s = 0; s < 5; ++s) {
        float wn[8];
        float sum = 0.0f;
#pragma unroll
        for (int j = 0; j < 8; ++j) {
            wn[j] = __expf(tanhf(uas[j] + ubs[s]));
            sum += wn[j];
        }
        float inv = 1.0f / sum;
        float av0 = 0.0f, av1 = 0.0f;
#pragma unroll
        for (int j = 0; j < 8; ++j) {
            av0 = fmaf(wn[j], ctx[j][c0], av0);
            av1 = fmaf(wn[j], ctx[j][c1], av1);
        }
        av0 *= inv;
        av1 *= inv;
        float d0 = av0 - (float)Hbf[(size_t)(b * 13 + 8 + s) * HDIM + c0];
        float d1 = av1 - (float)Hbf[(size_t)(b * 13 + 8 + s) * HDIM + c1];
        float v = d0 * d0 + d1 * d1;
#pragma unroll
        for (int o = 32; o > 0; o >>= 1) v += __shfl_down(v, o);
        if (lane == 0) red[wid] = v;
        __syncthreads();
        if (t == 0) outv[b * 5 + s] = -sqrtf(red[0] + red[1] + red[2] + red[3]);
        __syncthreads();
    }
}

extern "C" void kernel_launch(void* const* d_in, const int* in_sizes, int n_in,
                              void* d_out, int out_size, void* d_ws, size_t ws_size,
                              hipStream_t stream) {
    const float* Ain  = (const float*)d_in[0];
    const int*   ids  = (const int*)d_in[1];
    const float* emb  = (const float*)d_in[2];
    const float* b_ah = (const float*)d_in[3];
    const float* w_z  = (const float*)d_in[4];
    const float* b_wz = (const float*)d_in[5];
    const float* u_z  = (const float*)d_in[6];
    const float* b_uz = (const float*)d_in[7];
    const float* w_r  = (const float*)d_in[8];
    const float* b_wr = (const float*)d_in[9];
    const float* u_r  = (const float*)d_in[10];
    const float* b_ur = (const float*)d_in[11];
    const float* w_   = (const float*)d_in[12];
    const float* b_w  = (const float*)d_in[13];
    const float* u_u  = (const float*)d_in[14];
    const float* b_u  = (const float*)d_in[15];
    const float* w1   = (const float*)d_in[16];
    const float* b1   = (const float*)d_in[17];
    const float* w12  = (const float*)d_in[18];
    const float* b12  = (const float*)d_in[19];
    const float* w2   = (const float*)d_in[20];
    const float* b2   = (const float*)d_in[21];
    const float* w22  = (const float*)d_in[22];
    const float* b22  = (const float*)d_in[23];
    float* out = (float*)d_out;

    // ---- chunk size: rows=13C divisible by 128 -> C multiple of 128 ----
    // per-elem: Hbf2 + Abf2 + RHbf2 + Zbf2 = 8B
    int C = 128;
    {
        const int cands[6] = {4096, 2048, 1024, 512, 256, 128};
        for (int ci = 0; ci < 6; ++ci) {
            int cc = cands[ci];
            size_t rows = (size_t)13 * cc;
            size_t need = rows * 512 * 8
                        + 6 * (size_t)262144 * 2
                        + 2 * (size_t)131072 * 2
                        + (size_t)13 * cc * 4
                        + (4u << 20);
            if (need <= ws_size) { C = cc; break; }
        }
    }
    const int rows = 13 * C;

    char* base = (char*)d_ws;
    __bf16* Wzb = (__bf16*)base; base += 262144 * 2;
    __bf16* Uzb = (__bf16*)base; base += 262144 * 2;
    __bf16* Wrb = (__bf16*)base; base += 262144 * 2;
    __bf16* Urb = (__bf16*)base; base += 262144 * 2;
    __bf16* Wb  = (__bf16*)base; base += 262144 * 2;
    __bf16* Ub  = (__bf16*)base; base += 262144 * 2;
    __bf16* W1b = (__bf16*)base; base += 131072 * 2;
    __bf16* W2b = (__bf16*)base; base += 131072 * 2;
    float* UA  = (float*)base; base += (size_t)8 * C * 4;
    float* UB  = (float*)base; base += (size_t)5 * C * 4;
    __bf16* Hbf  = (__bf16*)base; base += (size_t)rows * 512 * 2;
    __bf16* Abf  = (__bf16*)base; base += (size_t)rows * 512 * 2;
    __bf16* RHbf = (__bf16*)base; base += (size_t)rows * 512 * 2;
    __bf16* Zbf  = (__bf16*)base; base += (size_t)rows * 512 * 2;

    f2bf_all<<<7168, 256, 0, stream>>>(w_z, u_z, w_r, u_r, w_, u_u, w1, w2,
                                       Wzb, Uzb, Wrb, Urb, Wb, Ub, W1b, W2b);

    int nblk4 = (rows / 128) * 4;
    int nblkA = 8 * C / 128;
    int nblkB = 5 * C / 128;
    for (int g0 = 0; g0 < 4096; g0 += C) {
        gather_a<<<C, 256, 0, stream>>>(ids + (size_t)g0 * 52, emb,
                                        Ain + (size_t)g0 * 169, b_ah, Hbf, Abf);
        zr_fused<<<nblk4, 512, 0, stream>>>(Abf, Hbf, Wzb, Uzb, Wrb, Urb,
                                            b_wz, b_uz, b_wr, b_ur, Zbf, RHbf);
        c_fused<<<nblk4, 512, 0, stream>>>(Abf, RHbf, Wb, Ub, b_w, b_u, Zbf, Hbf);
        a_kernel<<<C, 256, 0, stream>>>(Ain + (size_t)g0 * 169, Hbf, b_ah, Abf);
        zr_fused<<<nblk4, 512, 0, stream>>>(Abf, Hbf, Wzb, Uzb, Wrb, Urb,
                                            b_wz, b_uz, b_wr, b_ur, Zbf, RHbf);
        c_fused<<<nblk4, 512, 0, stream>>>(Abf, RHbf, Wb, Ub, b_w, b_u, Zbf, Hbf);

        score_mfma<<<nblkA + nblkB, 512, 0, stream>>>(Hbf, W1b, W2b, b1, b2, w12, w22,
                                                      b12, b22, UA, UB, nblkA);
        final_kernel<<<C, 256, 0, stream>>>(Hbf, UA, UB, out + (size_t)g0 * 5);
    }
}